// Round 17
// baseline (27.257 us; speedup 1.0000x reference)
//
#include <hip/hip_runtime.h>
#include <math.h>

// B=8, F=128, K=256, E=256, alpha=0.2
#define BB 8
#define FF 128
#define KK 256
#define EE 256
#define TI 4

typedef float f4 __attribute__((ext_vector_type(4)));
typedef float f2 __attribute__((ext_vector_type(2)));
typedef unsigned int   uint32;
typedef unsigned short ushort16;

__device__ __forceinline__ float rdl(float v, int l) {
  return __int_as_float(__builtin_amdgcn_readlane(__float_as_int(v), l));
}
__device__ __forceinline__ f2 splat2(float x) { return (f2){x, x}; }
// f32 -> bf16 with round-to-nearest-even (values finite; NaN not possible here)
__device__ __forceinline__ ushort16 f2bf(float f) {
  uint32 u = __float_as_uint(f);
  return (ushort16)((u + 0x7fffu + ((u >> 16) & 1u)) >> 16);
}
// unpack low/high bf16 of a u32 (2 consecutive shorts) to f32
__device__ __forceinline__ float bfl(uint32 u) { return __uint_as_float(u << 16); }
__device__ __forceinline__ float bfh(uint32 u) { return __uint_as_float(u & 0xffff0000u); }

// ---------------------------------------------------------------------------
// prep: p[b][k][e] f32 (+b_lin), qT[b][e][k] bf16, xT[b][k][f] bf16,
//       Q6[b][k] f32 (from f32 q). grid 256 (XCD-pinned) x 512 thr.
// ---------------------------------------------------------------------------
__global__ __launch_bounds__(512, 2) void prep_kernel(
    const float* __restrict__ x, const float* __restrict__ W,
    const float* __restrict__ b_lin, const float* __restrict__ a,
    float* __restrict__ p, ushort16* __restrict__ qTb,
    ushort16* __restrict__ xTb, float* __restrict__ Q6) {
  __shared__ float xs[FF][8];
  __shared__ float part[16][EE];

  const int b  = blockIdx.x & 7;          // XCD = blockIdx % 8 = b
  const int k0 = (blockIdx.x >> 3) * 8;
  const int t  = threadIdx.x;

  {
    const float* xb = x + b * FF * KK + k0;
    const int f = t >> 3, u = t & 7;
    xs[f][u]      = xb[f * KK + u];
    xs[f + 64][u] = xb[(f + 64) * KK + u];
  }
  __syncthreads();

  // xT bf16: thread (k=u, f-pair) packs 2 shorts -> u32 store
  {
    const int u = t >> 6, f2i = (t & 63) * 2;
    const uint32 xw = (uint32)f2bf(xs[f2i][u]) | ((uint32)f2bf(xs[f2i + 1][u]) << 16);
    *(uint32*)&xTb[(b * KK + k0 + u) * FF + f2i] = xw;
  }

  const int e = t & 255, fh = t >> 8;
  float pacc[8] = {0,0,0,0,0,0,0,0}, qacc[8] = {0,0,0,0,0,0,0,0};
  {
    const float* Wp = W + (fh * 64) * EE + e;
    const float* Wq = W + (FF + fh * 64) * EE + e;
    const float* xr = &xs[fh * 64][0];
#pragma unroll 8
    for (int ff = 0; ff < 64; ++ff) {
      const float w1 = Wp[ff * EE];
      const float w2 = Wq[ff * EE];
      const f4 xv0 = *(const f4*)(xr + ff * 8);
      const f4 xv1 = *(const f4*)(xr + ff * 8 + 4);
#pragma unroll
      for (int u = 0; u < 4; ++u) {
        pacc[u]     = fmaf(xv0[u], w1, pacc[u]);
        qacc[u]     = fmaf(xv0[u], w2, qacc[u]);
        pacc[4 + u] = fmaf(xv1[u], w1, pacc[4 + u]);
        qacc[4 + u] = fmaf(xv1[u], w2, qacc[4 + u]);
      }
    }
  }

  if (fh == 1) {
#pragma unroll
    for (int u = 0; u < 8; ++u) { part[u][e] = pacc[u]; part[8 + u][e] = qacc[u]; }
  }
  __syncthreads();
  if (fh == 0) {
    const float bl = b_lin[e], ae = a[e];
#pragma unroll
    for (int u = 0; u < 8; ++u) {
      const float pv = pacc[u] + part[u][e] + bl;
      const float qv = qacc[u] + part[8 + u][e];
      p[(b * KK + k0 + u) * EE + e] = pv;
      part[u][e]     = ae * qv;      // f32 for Q6 (keeps Q6 exact)
      part[8 + u][e] = qv;           // f32 staging for qT pack
    }
  }
  __syncthreads();

  // qT bf16: thread (e = t>>1, k-quad) packs 4 shorts -> u32x2 store
  {
    const int ee = t >> 1, k4 = (t & 1) * 4;
    const uint32 lo = (uint32)f2bf(part[8 + k4 + 0][ee]) |
                      ((uint32)f2bf(part[8 + k4 + 1][ee]) << 16);
    const uint32 hi = (uint32)f2bf(part[8 + k4 + 2][ee]) |
                      ((uint32)f2bf(part[8 + k4 + 3][ee]) << 16);
    uint2 v; v.x = lo; v.y = hi;
    *(uint2*)&qTb[(b * EE + ee) * KK + k0 + k4] = v;
  }

  // Q6 from f32 q
  {
    const int w = t >> 6, lane = t & 63;
    float s = part[w][lane] + part[w][lane + 64] + part[w][lane + 128] + part[w][lane + 192];
#pragma unroll
    for (int off = 32; off; off >>= 1) s += __shfl_xor(s, off, 64);
    if (lane == 0) Q6[b * KK + k0 + w] = 0.6f * s;
  }
}

// ---------------------------------------------------------------------------
// attn v14 = r9 structure (27.1us best) with bf16 qT/xT: stream bytes halved.
// grid 512 = it*8 + b (XCD-pinned), 512 thr (8 waves), lb(512,4).
// P1: wave (eq, jh): e in [64eq,+64), j = jh*128+2*lane+{0,1} (u32 bf16x2
//     loads), all 4 i; rotation pipeline; unpack = 2 VALU per e-row.
// P2: waves 0..3: softmax row i=w, 4-slice reduce fused.
// P3: wave w: j in [32w,+32), all 4 i, x as bf16x2; readlane bcast.
// ---------------------------------------------------------------------------
__global__ __launch_bounds__(512, 4) void attn_kernel(
    const float* __restrict__ p, const ushort16* __restrict__ qTb,
    const ushort16* __restrict__ xTb, const float* __restrict__ Q6,
    const float* __restrict__ a, const float* __restrict__ bias,
    float* __restrict__ out) {
  __shared__ float pt[TI][EE];         // 4KB
  __shared__ float a_s[EE];            // 1KB
  __shared__ float red[4][TI][KK];     // 16KB e-quarter partials
  __shared__ float sc[TI][KK];         // 4KB attn weights
  __shared__ float pvp[8][TI][132];    // 16.5KB PV partials (padded)

  const int b    = blockIdx.x & 7;     // XCD = b
  const int i0   = (blockIdx.x >> 3) * TI;
  const int t    = threadIdx.x;
  const int w    = t >> 6;
  const int lane = t & 63;

  // ---- phase 0: stage p-tile + a ----
  if (t < 256) {
    const int i = t >> 6, e4 = (t & 63) * 4;
    *(f4*)&pt[i][e4] = *(const f4*)&p[(b * KK + i0 + i) * EE + e4];
  } else if (t < 320) {
    const int e4 = (t - 256) * 4;
    *(f4*)&a_s[e4] = *(const f4*)&a[e4];
  }

  // ---- phase 1 prologue: preload chunk 0 (global, barrier-independent) ----
  const int eq = w >> 1, jh = w & 1;
  const int e0 = eq * 64;
  const ushort16* qc = qTb + (b * EE + e0) * KK + jh * 128 + 2 * lane;
  uint32 u0 = *(const uint32*)(qc);
  uint32 u1 = *(const uint32*)(qc + KK);
  uint32 u2 = *(const uint32*)(qc + 2 * KK);
  uint32 u3 = *(const uint32*)(qc + 3 * KK);
  qc += 4 * KK;
  __syncthreads();

  // ---- phase 1: rotation pipeline (load c+1 while computing c) ----
  {
    f2 acc[TI];
#pragma unroll
    for (int i = 0; i < TI; ++i) acc[i] = (f2){0.f, 0.f};
#pragma unroll 4
    for (int c = 0; c < 16; ++c) {
      // next-chunk loads (c=15 overreads into adjacent ws region: benign)
      const uint32 n0 = *(const uint32*)(qc);
      const uint32 n1 = *(const uint32*)(qc + KK);
      const uint32 n2 = *(const uint32*)(qc + 2 * KK);
      const uint32 n3 = *(const uint32*)(qc + 3 * KK);
      qc += 4 * KK;
      // unpack current chunk (2 VALU per e-row)
      f2 q0; q0.x = bfl(u0); q0.y = bfh(u0);
      f2 q1; q1.x = bfl(u1); q1.y = bfh(u1);
      f2 q2; q2.x = bfl(u2); q2.y = bfh(u2);
      f2 q3; q3.x = bfl(u3); q3.y = bfh(u3);
      const f4 av = *(const f4*)&a_s[e0 + 4 * c];      // uniform LDS b128
#pragma unroll
      for (int i = 0; i < TI; ++i) {
        const f4 pv = *(const f4*)&pt[i][e0 + 4 * c];  // uniform LDS b128
        acc[i].x = fmaf(fabsf(q0.x + pv[0]), av[0], acc[i].x);  // abs = VOP3 mod
        acc[i].y = fmaf(fabsf(q0.y + pv[0]), av[0], acc[i].y);
        acc[i].x = fmaf(fabsf(q1.x + pv[1]), av[1], acc[i].x);
        acc[i].y = fmaf(fabsf(q1.y + pv[1]), av[1], acc[i].y);
        acc[i].x = fmaf(fabsf(q2.x + pv[2]), av[2], acc[i].x);
        acc[i].y = fmaf(fabsf(q2.y + pv[2]), av[2], acc[i].y);
        acc[i].x = fmaf(fabsf(q3.x + pv[3]), av[3], acc[i].x);
        acc[i].y = fmaf(fabsf(q3.y + pv[3]), av[3], acc[i].y);
      }
      u0 = n0; u1 = n1; u2 = n2; u3 = n3;
    }
    const int jb = jh * 128 + 2 * lane;
#pragma unroll
    for (int i = 0; i < TI; ++i)
      *(f2*)&red[eq][i][jb] = acc[i];        // b64, conflict-free
  }
  __syncthreads();

  // ---- phase 3 prologue: first x-load in flight during softmax ----
  const int j0 = 32 * w;
  const ushort16* xb = xTb + (b * KK + j0) * FF + 2 * lane;
  uint32 xu = *(const uint32*)(xb);

  // ---- phase 2: softmax rows (waves 0..3, row i=w), reduce fused ----
  if (w < TI) {
    const int i = w;
    f4 s = (f4){0.f, 0.f, 0.f, 0.f};
#pragma unroll
    for (int e8 = 0; e8 < 4; ++e8)
      s += *(const f4*)&red[e8][i][4 * lane];
    const f4 q6 = *(const f4*)&Q6[b * KK + 4 * lane];
    const f4 bv = *(const f4*)&bias[(i0 + i) * KK + 4 * lane];
    f4 ev;
#pragma unroll
    for (int v = 0; v < 4; ++v)
      ev[v] = __expf(0.4f * s[v] + q6[v] + bv[v]);  // |score| < ~10: exp safe
    float tot = ev[0] + ev[1] + ev[2] + ev[3];
#pragma unroll
    for (int off = 32; off; off >>= 1) tot += __shfl_xor(tot, off, 64);
    const float inv = 1.f / tot;
#pragma unroll
    for (int v = 0; v < 4; ++v) ev[v] *= inv;
    *(f4*)&sc[i][4 * lane] = ev;
  }
  __syncthreads();

  // ---- phase 3: PV with rotation. wave w: j in [32w,+32), f = 2*lane+{0,1} ----
  {
    float rv[TI];
#pragma unroll
    for (int i = 0; i < TI; ++i) rv[i] = sc[i][j0 + (lane & 31)];  // 2-way, free
    f2 pacc[TI];
#pragma unroll
    for (int i = 0; i < TI; ++i) pacc[i] = (f2){0.f, 0.f};
#pragma unroll 4
    for (int jj = 0; jj < 32; ++jj) {
      const uint32 nx = *(const uint32*)(xb + (jj + 1) * FF);  // next (overread benign)
      f2 xv; xv.x = bfl(xu); xv.y = bfh(xu);
#pragma unroll
      for (int i = 0; i < TI; ++i) {
        const float sv = rdl(rv[i], jj);          // imm-lane readlane (VALU)
        pacc[i].x = fmaf(sv, xv.x, pacc[i].x);
        pacc[i].y = fmaf(sv, xv.y, pacc[i].y);
      }
      xu = nx;
    }
#pragma unroll
    for (int i = 0; i < TI; ++i)
      *(f2*)&pvp[w][i][2 * lane] = pacc[i];
  }
  __syncthreads();

  // ---- combine 8 j-windows + sigmoid + store ----
  {
    const int f = t >> 2, i = t & 3;
    float s = 0.f;
#pragma unroll
    for (int jo = 0; jo < 8; ++jo) s += pvp[jo][i][f];
    out[(b * FF + f) * KK + i0 + i] = 1.f / (1.f + __expf(-s));
  }
}

extern "C" void kernel_launch(void* const* d_in, const int* in_sizes, int n_in,
                              void* d_out, int out_size, void* d_ws, size_t ws_size,
                              hipStream_t stream) {
  const float* x     = (const float*)d_in[0];
  const float* W     = (const float*)d_in[1];
  const float* b_lin = (const float*)d_in[2];
  const float* a     = (const float*)d_in[3];
  const float* bias  = (const float*)d_in[4];
  float* out = (float*)d_out;

  float*    p   = (float*)d_ws;                     // [B,K,E] f32, 2MB
  ushort16* qTb = (ushort16*)(p + BB * KK * EE);    // [B,E,K] bf16, 1MB
  ushort16* xTb = qTb + BB * EE * KK;               // [B,K,F] bf16, 0.5MB
  float*    Q6  = (float*)(xTb + BB * KK * FF);     // [B,K] f32, 8KB

  prep_kernel<<<(KK / 8) * 8, 512, 0, stream>>>(x, W, b_lin, a, p, qTb, xTb, Q6);
  attn_kernel<<<(KK / TI) * 8, 512, 0, stream>>>(p, qTb, xTb, Q6, a, bias, out);
}